// Round 4
// baseline (508.599 us; speedup 1.0000x reference)
//
#include <hip/hip_runtime.h>
#include <hip/hip_bf16.h>
#include <math.h>

// MFGN forward, MI355X. One block (512 thr, 8 waves) per outfit.
// Waves = 2 row-groups (mg) x 4 col-groups (ng, 32 cols each).
// L1 operand-swapped (A=W1^T, B=X^T) so hidden lands packable (4 consecutive
// e per lane) -> b64 row-major writes; L2 normal (A=hid, B=W2).
// Per-step barriers: stage -> B -> L1+hid -> B -> L2+epilogue -> B.

typedef __attribute__((ext_vector_type(8))) short short8;
typedef __attribute__((ext_vector_type(4))) float f32x4;

#define MFMA16(a, b, c) __builtin_amdgcn_mfma_f32_16x16x32_bf16(a, b, c, 0, 0, 0)

__device__ __forceinline__ float lrelu(float x) { return x > 0.0f ? x : 0.01f * x; }

__device__ __forceinline__ ushort f2bf(float f) {
  unsigned u = __builtin_bit_cast(unsigned, f);
  u += 0x7fffu + ((u >> 16) & 1u);  // RNE
  return (ushort)(u >> 16);
}

// packed f32x2 -> bf16x2 (v_cvt_pk_bf16_f32); low ushort = a
__device__ __forceinline__ unsigned pk2(float a, float b) {
  float2 t; t.x = a; t.y = b;
  __hip_bfloat162 h = __float22bfloat162_rn(t);
  unsigned u;
  __builtin_memcpy(&u, &h, 4);  // __hip_bfloat162 not trivially copyable -> no bit_cast
  return u;
}

// B-fragment gather from row-major fp32 W[k][ldn]: lane j -> W[kbase+j][col]
__device__ __forceinline__ short8 load_bfrag(const float* __restrict__ W, int ldn,
                                             int kbase, int col) {
  short8 r;
#pragma unroll
  for (int j = 0; j < 8; ++j) r[j] = (short)f2bf(W[(kbase + j) * ldn + col]);
  return r;
}

__global__ void zero_com(float* out) { if (threadIdx.x == 0) out[2048] = 0.0f; }

__global__ __launch_bounds__(512, 4) void mfgn_kernel(
    const int* __restrict__ outfit_items,
    const float* __restrict__ items_feature,
    const int* __restrict__ items_neighbor,
    const float* __restrict__ cfW1, const float* __restrict__ cfb1,
    const float* __restrict__ cfW2, const float* __restrict__ cfb2,
    const float* __restrict__ f2fW1, const float* __restrict__ f2fb1,
    const float* __restrict__ f2fW2, const float* __restrict__ f2fb2,
    const float* __restrict__ f2iW1, const float* __restrict__ f2ib1,
    const float* __restrict__ f2iW2, const float* __restrict__ f2ib2,
    const float* __restrict__ i2iW1, const float* __restrict__ i2ib1,
    const float* __restrict__ i2iW2, const float* __restrict__ i2ib2,
    const float* __restrict__ o2sW, const float* __restrict__ o2sb,
    float* __restrict__ out)
{
  __shared__ float facL[16 * 528];                               // fp32 [item][f][132]
  __shared__ float featL[16 * 132];                              // fp32 [item][132]
  __shared__ ushort Xa[64 * 136] __attribute__((aligned(16)));   // bf16 X rows (stride 272B)
  __shared__ ushort hidB[64 * 136] __attribute__((aligned(16))); // bf16 hidden rows
  __shared__ float redE[8];
  __shared__ int oiL[16];
  __shared__ int nbrL[128];
  __shared__ int clAll[16 * 16];
  __shared__ int ncAll[16];
  __shared__ int vslL[16];
  __shared__ int refcntL[16];
  __shared__ int nvsL;

  const int o = blockIdx.x;
  const int tid = (int)threadIdx.x;
  const int lane = tid & 63;
  const int wid = tid >> 6;       // 0..7
  const int ng = wid & 3;         // col-group: cols ng*32..+31
  const int mg = wid >> 2;        // row-group: rows mg*32..+31
  const int n16 = lane & 15;
  const int q = lane >> 4;
  const int kb = q * 8;

  // ---------------- load inputs ----------------
  if (tid < 16) oiL[tid] = outfit_items[o * 16 + tid];
  if (tid < 128) nbrL[tid] = items_neighbor[o * 128 + tid];
  {
    const int n = tid >> 5, d0 = (tid & 31) * 4;
    float4 v = *(const float4*)(items_feature + o * 2048 + tid * 4);
    *(float4*)(featL + n * 132 + d0) = v;
    uint2 pk; pk.x = pk2(v.x, v.y); pk.y = pk2(v.z, v.w);
    *(uint2*)(Xa + n * 136 + d0) = pk;  // featB rows 0..15
  }
  if (tid == 0) {
    int cnt = 0;
    for (int s = 0; s < 16; ++s) refcntL[s] = 0;
    for (int s = 0; s < 16; ++s) {
      int v = oiL[s];
      if (v != -1) { vslL[cnt++] = s; refcntL[v]++; }
    }
    nvsL = cnt;
  }
  for (int s = wid; s < 16; s += 8) {
    const int iv = outfit_items[o * 16 + s];
    if (iv == -1) { if (lane == 0) ncAll[s] = 0; continue; }
    int cand = -1;
    if (lane < 24) cand = (lane < 16) ? outfit_items[o * 16 + lane]
                                      : items_neighbor[o * 128 + iv * 8 + (lane - 16)];
    bool ok = (lane < 24) && (cand != -1) && (cand != iv);
    unsigned long long bm = __ballot(ok);
    if (ok) clAll[s * 16 + __popcll(bm & ((1ull << lane) - 1ull))] = cand;
    if (lane == 0) ncAll[s] = (int)__popcll(bm);
  }
  __syncthreads();
  const int nvs = nvsL;

  // ---------------- Phase A: creat_factors ----------------
  {
    const int f = wid & 3, half = wid >> 2;
    // L1 swapped: H^T = W1^T * X^T ; wave covers 32 of 64 hidden cols
    short8 wA[2][4];
#pragma unroll
    for (int etl = 0; etl < 2; ++etl)
#pragma unroll
      for (int kt = 0; kt < 4; ++kt)
        wA[etl][kt] = load_bfrag(cfW1 + f * 8192, 64, kt * 32 + kb, (half * 2 + etl) * 16 + n16);
    f32x4 acc[2];
    acc[0] = (f32x4){0.f,0.f,0.f,0.f}; acc[1] = (f32x4){0.f,0.f,0.f,0.f};
    for (int kt = 0; kt < 4; ++kt) {
      short8 x = *(const short8*)(Xa + n16 * 136 + kt * 32 + kb);
      acc[0] = MFMA16(wA[0][kt], x, acc[0]);
      acc[1] = MFMA16(wA[1][kt], x, acc[1]);
    }
#pragma unroll
    for (int etl = 0; etl < 2; ++etl) {
      f32x4 b1q = *(const f32x4*)(cfb1 + f * 64 + (half * 2 + etl) * 16 + q * 4);
      float h0 = lrelu(acc[etl][0] + b1q[0]), h1 = lrelu(acc[etl][1] + b1q[1]);
      float h2 = lrelu(acc[etl][2] + b1q[2]), h3 = lrelu(acc[etl][3] + b1q[3]);
      uint2 pk; pk.x = pk2(h0, h1); pk.y = pk2(h2, h3);
      *(uint2*)(hidB + (f * 16 + n16) * 136 + (half * 2 + etl) * 16 + q * 4) = pk;
    }
    __syncthreads();
    // L2 normal: fac = H * W2[f], K=64 ; wave covers 64 of 128 cols
    short8 wB[4][2];
#pragma unroll
    for (int ctl = 0; ctl < 4; ++ctl)
#pragma unroll
      for (int kt = 0; kt < 2; ++kt)
        wB[ctl][kt] = load_bfrag(cfW2 + f * 8192, 128, kt * 32 + kb, half * 64 + ctl * 16 + n16);
    f32x4 acc2[4];
#pragma unroll
    for (int ctl = 0; ctl < 4; ++ctl) acc2[ctl] = (f32x4){0.f,0.f,0.f,0.f};
    for (int kt = 0; kt < 2; ++kt) {
      short8 h = *(const short8*)(hidB + (f * 16 + n16) * 136 + kt * 32 + kb);
#pragma unroll
      for (int ctl = 0; ctl < 4; ++ctl) acc2[ctl] = MFMA16(h, wB[ctl][kt], acc2[ctl]);
    }
#pragma unroll
    for (int ctl = 0; ctl < 4; ++ctl) {
      int c = half * 64 + ctl * 16 + n16;
      float b2 = cfb2[f * 128 + c];
#pragma unroll
      for (int r = 0; r < 4; ++r)
        facL[(q * 4 + r) * 528 + f * 132 + c] = lrelu(acc2[ctl][r] + b2);
    }
    __syncthreads();
  }

  // ---------------- Phase B: inter_factors ----------------
  {
    short8 w1f[2][4], w2f[2][4];
#pragma unroll
    for (int ntl = 0; ntl < 2; ++ntl)
#pragma unroll
      for (int kt = 0; kt < 4; ++kt) {
        w1f[ntl][kt] = load_bfrag(f2fW1, 128, kt * 32 + kb, (ng * 2 + ntl) * 16 + n16);
        w2f[ntl][kt] = load_bfrag(f2fW2, 128, kt * 32 + kb, (ng * 2 + ntl) * 16 + n16);
      }
    f32x4 b1q[2];
    float b2v[2];
#pragma unroll
    for (int ntl = 0; ntl < 2; ++ntl) {
      b1q[ntl] = *(const f32x4*)(f2fb1 + (ng * 2 + ntl) * 16 + q * 4);
      b2v[ntl] = f2fb2[(ng * 2 + ntl) * 16 + n16];
    }
    const int rS = tid >> 3, kcS = tid & 7;      // staging: row, 16-k chunk
    const int fS = rS & 3, ciS = rS >> 2;
    const int k0 = kcS * 16;

    for (int s = 0; s < 16; ++s) {
      const int iv = oiL[s];
      if (iv == -1) continue;
      const int nc = ncAll[s];
      // stage Xa[r=ci*4+f][k] = bf16(fac[iv][f][k] * fac[cand][f][k])
      if (ciS < nc) {
        const int cit = clAll[s * 16 + ciS];
        const float* tp = facL + iv * 528 + fS * 132;
        const float* cp = facL + cit * 528 + fS * 132;
#pragma unroll
        for (int i2 = 0; i2 < 2; ++i2) {
          const int k = k0 + i2 * 8;
          float4 a0 = *(const float4*)(tp + k), a1 = *(const float4*)(tp + k + 4);
          float4 c0 = *(const float4*)(cp + k), c1 = *(const float4*)(cp + k + 4);
          uint4 u;
          u.x = pk2(a0.x * c0.x, a0.y * c0.y); u.y = pk2(a0.z * c0.z, a0.w * c0.w);
          u.z = pk2(a1.x * c1.x, a1.y * c1.y); u.w = pk2(a1.z * c1.z, a1.w * c1.w);
          *(uint4*)(Xa + rS * 136 + k) = u;
        }
      } else {
        uint4 z; z.x = z.y = z.z = z.w = 0;
        *(uint4*)(Xa + rS * 136 + k0) = z;
        *(uint4*)(Xa + rS * 136 + k0 + 8) = z;
      }
      __syncthreads();
      // L1 swapped: lane -> H[row=mg*32+mt*16+n16][e=(ng*2+ntl)*16+q*4+reg]
      f32x4 acc[2][2];
#pragma unroll
      for (int mt = 0; mt < 2; ++mt) { acc[mt][0] = (f32x4){0.f,0.f,0.f,0.f}; acc[mt][1] = (f32x4){0.f,0.f,0.f,0.f}; }
      for (int kt = 0; kt < 4; ++kt)
#pragma unroll
        for (int mt = 0; mt < 2; ++mt) {
          short8 x = *(const short8*)(Xa + (mg * 32 + mt * 16 + n16) * 136 + kt * 32 + kb);
          acc[mt][0] = MFMA16(w1f[0][kt], x, acc[mt][0]);
          acc[mt][1] = MFMA16(w1f[1][kt], x, acc[mt][1]);
        }
#pragma unroll
      for (int mt = 0; mt < 2; ++mt)
#pragma unroll
        for (int ntl = 0; ntl < 2; ++ntl) {
          float h0 = lrelu(acc[mt][ntl][0] + b1q[ntl][0]);
          float h1 = lrelu(acc[mt][ntl][1] + b1q[ntl][1]);
          float h2 = lrelu(acc[mt][ntl][2] + b1q[ntl][2]);
          float h3 = lrelu(acc[mt][ntl][3] + b1q[ntl][3]);
          uint2 pk; pk.x = pk2(h0, h1); pk.y = pk2(h2, h3);
          *(uint2*)(hidB + (mg * 32 + mt * 16 + n16) * 136 + (ng * 2 + ntl) * 16 + q * 4) = pk;
        }
      __syncthreads();
      // L2 normal: lane -> Y[r=mg*32+mt*16+q*4+reg][c=(ng*2+ntl)*16+n16]
      f32x4 acc2[2][2];
#pragma unroll
      for (int mt = 0; mt < 2; ++mt) { acc2[mt][0] = (f32x4){0.f,0.f,0.f,0.f}; acc2[mt][1] = (f32x4){0.f,0.f,0.f,0.f}; }
      for (int kt = 0; kt < 4; ++kt)
#pragma unroll
        for (int mt = 0; mt < 2; ++mt) {
          short8 h = *(const short8*)(hidB + (mg * 32 + mt * 16 + n16) * 136 + kt * 32 + kb);
          acc2[mt][0] = MFMA16(h, w2f[0][kt], acc2[mt][0]);
          acc2[mt][1] = MFMA16(h, w2f[1][kt], acc2[mt][1]);
        }
      float part[2][4];
#pragma unroll
      for (int ntl = 0; ntl < 2; ++ntl)
#pragma unroll
        for (int r = 0; r < 4; ++r) part[ntl][r] = 0.0f;
#pragma unroll
      for (int mt = 0; mt < 2; ++mt) {
        bool act = (mg * 8 + mt * 4 + q) < nc;
        if (act)
#pragma unroll
          for (int ntl = 0; ntl < 2; ++ntl)
#pragma unroll
            for (int r = 0; r < 4; ++r)
              part[ntl][r] += lrelu(acc2[mt][ntl][r] + b2v[ntl]);
      }
#pragma unroll
      for (int ntl = 0; ntl < 2; ++ntl)
#pragma unroll
        for (int r = 0; r < 4; ++r) {
          float v = part[ntl][r];
          v += __shfl_xor(v, 16);
          v += __shfl_xor(v, 32);
          part[ntl][r] = v;
        }
      if (q == 0) {
#pragma unroll
        for (int ntl = 0; ntl < 2; ++ntl)
#pragma unroll
          for (int r = 0; r < 4; ++r)
            atomicAdd(&facL[iv * 528 + r * 132 + (ng * 2 + ntl) * 16 + n16], part[ntl][r]);
      }
      __syncthreads();
    }
  }

  // ---------------- Phase C: infer_items ----------------
  {
    short8 w1f[2][4], w2f[2][4];
#pragma unroll
    for (int ntl = 0; ntl < 2; ++ntl)
#pragma unroll
      for (int kt = 0; kt < 4; ++kt) {
        w1f[ntl][kt] = load_bfrag(f2iW1, 128, kt * 32 + kb, (ng * 2 + ntl) * 16 + n16);
        w2f[ntl][kt] = load_bfrag(f2iW2, 128, kt * 32 + kb, (ng * 2 + ntl) * 16 + n16);
      }
    f32x4 b1q[2];
    float b2v[2];
#pragma unroll
    for (int ntl = 0; ntl < 2; ++ntl) {
      b1q[ntl] = *(const f32x4*)(f2ib1 + (ng * 2 + ntl) * 16 + q * 4);
      b2v[ntl] = f2ib2[(ng * 2 + ntl) * 16 + n16];
    }
    // stage Xa[r=item*4+f][k] = bf16(fac[item][f][k])
    {
      const int r = tid >> 3, kc = tid & 7, k0 = kc * 16;
      const int f = r & 3, item = r >> 2;
      const float* sp = facL + item * 528 + f * 132;
#pragma unroll
      for (int i2 = 0; i2 < 2; ++i2) {
        const int k = k0 + i2 * 8;
        float4 a0 = *(const float4*)(sp + k), a1 = *(const float4*)(sp + k + 4);
        uint4 u;
        u.x = pk2(a0.x, a0.y); u.y = pk2(a0.z, a0.w);
        u.z = pk2(a1.x, a1.y); u.w = pk2(a1.z, a1.w);
        *(uint4*)(Xa + r * 136 + k) = u;
      }
    }
    __syncthreads();
    f32x4 acc[2][2];
#pragma unroll
    for (int mt = 0; mt < 2; ++mt) { acc[mt][0] = (f32x4){0.f,0.f,0.f,0.f}; acc[mt][1] = (f32x4){0.f,0.f,0.f,0.f}; }
    for (int kt = 0; kt < 4; ++kt)
#pragma unroll
      for (int mt = 0; mt < 2; ++mt) {
        short8 x = *(const short8*)(Xa + (mg * 32 + mt * 16 + n16) * 136 + kt * 32 + kb);
        acc[mt][0] = MFMA16(w1f[0][kt], x, acc[mt][0]);
        acc[mt][1] = MFMA16(w1f[1][kt], x, acc[mt][1]);
      }
#pragma unroll
    for (int mt = 0; mt < 2; ++mt)
#pragma unroll
      for (int ntl = 0; ntl < 2; ++ntl) {
        float h0 = lrelu(acc[mt][ntl][0] + b1q[ntl][0]);
        float h1 = lrelu(acc[mt][ntl][1] + b1q[ntl][1]);
        float h2 = lrelu(acc[mt][ntl][2] + b1q[ntl][2]);
        float h3 = lrelu(acc[mt][ntl][3] + b1q[ntl][3]);
        uint2 pk; pk.x = pk2(h0, h1); pk.y = pk2(h2, h3);
        *(uint2*)(hidB + (mg * 32 + mt * 16 + n16) * 136 + (ng * 2 + ntl) * 16 + q * 4) = pk;
      }
    __syncthreads();
    f32x4 acc2[2][2];
#pragma unroll
    for (int mt = 0; mt < 2; ++mt) { acc2[mt][0] = (f32x4){0.f,0.f,0.f,0.f}; acc2[mt][1] = (f32x4){0.f,0.f,0.f,0.f}; }
    for (int kt = 0; kt < 4; ++kt)
#pragma unroll
      for (int mt = 0; mt < 2; ++mt) {
        short8 h = *(const short8*)(hidB + (mg * 32 + mt * 16 + n16) * 136 + kt * 32 + kb);
        acc2[mt][0] = MFMA16(h, w2f[0][kt], acc2[mt][0]);
        acc2[mt][1] = MFMA16(h, w2f[1][kt], acc2[mt][1]);
      }
#pragma unroll
    for (int mt = 0; mt < 2; ++mt) {
      int item = mg * 8 + mt * 4 + q;
      float rc = (float)refcntL[item];
#pragma unroll
      for (int ntl = 0; ntl < 2; ++ntl) {
        float g = 0.f;
#pragma unroll
        for (int r = 0; r < 4; ++r) g += lrelu(acc2[mt][ntl][r] + b2v[ntl]);
        featL[item * 132 + (ng * 2 + ntl) * 16 + n16] += rc * g;
      }
    }
    __syncthreads();
  }

  // ---------------- Phase D: inter_items ----------------
  {
    short8 w1f[2][4], w2f[2][4];
#pragma unroll
    for (int ntl = 0; ntl < 2; ++ntl)
#pragma unroll
      for (int kt = 0; kt < 4; ++kt) {
        w1f[ntl][kt] = load_bfrag(i2iW1, 128, kt * 32 + kb, (ng * 2 + ntl) * 16 + n16);
        w2f[ntl][kt] = load_bfrag(i2iW2, 128, kt * 32 + kb, (ng * 2 + ntl) * 16 + n16);
      }
    f32x4 b1q[2];
    float b2v[2];
#pragma unroll
    for (int ntl = 0; ntl < 2; ++ntl) {
      b1q[ntl] = *(const f32x4*)(i2ib1 + (ng * 2 + ntl) * 16 + q * 4);
      b2v[ntl] = i2ib2[(ng * 2 + ntl) * 16 + n16];
    }
    const int rS = tid >> 3, kcS = tid & 7, k0 = kcS * 16;

    for (int u = 0; u < nvs; ++u) {
      const int iv = oiL[vslL[u]];
      // stage Xa rows j<nvs from current feat
      if (rS < nvs) {
        const int it = oiL[vslL[rS]];
        const float* sp = featL + it * 132;
#pragma unroll
        for (int i2 = 0; i2 < 2; ++i2) {
          const int k = k0 + i2 * 8;
          float4 a0 = *(const float4*)(sp + k), a1 = *(const float4*)(sp + k + 4);
          uint4 uu;
          uu.x = pk2(a0.x, a0.y); uu.y = pk2(a0.z, a0.w);
          uu.z = pk2(a1.x, a1.y); uu.w = pk2(a1.z, a1.w);
          *(uint4*)(Xa + rS * 136 + k) = uu;
        }
      }
      __syncthreads();
      if (mg == 0) {
        f32x4 acc[2];
        acc[0] = (f32x4){0.f,0.f,0.f,0.f}; acc[1] = (f32x4){0.f,0.f,0.f,0.f};
        for (int kt = 0; kt < 4; ++kt) {
          short8 x = *(const short8*)(Xa + n16 * 136 + kt * 32 + kb);
          acc[0] = MFMA16(w1f[0][kt], x, acc[0]);
          acc[1] = MFMA16(w1f[1][kt], x, acc[1]);
        }
#pragma unroll
        for (int ntl = 0; ntl < 2; ++ntl) {
          float h0 = lrelu(acc[ntl][0] + b1q[ntl][0]);
          float h1 = lrelu(acc[ntl][1] + b1q[ntl][1]);
          float h2 = lrelu(acc[ntl][2] + b1q[ntl][2]);
          float h3 = lrelu(acc[ntl][3] + b1q[ntl][3]);
          uint2 pk; pk.x = pk2(h0, h1); pk.y = pk2(h2, h3);
          *(uint2*)(hidB + n16 * 136 + (ng * 2 + ntl) * 16 + q * 4) = pk;
        }
      }
      __syncthreads();
      if (mg == 0) {
        f32x4 acc2[2];
        acc2[0] = (f32x4){0.f,0.f,0.f,0.f}; acc2[1] = (f32x4){0.f,0.f,0.f,0.f};
        for (int kt = 0; kt < 4; ++kt) {
          short8 h = *(const short8*)(hidB + n16 * 136 + kt * 32 + kb);
          acc2[0] = MFMA16(h, w2f[0][kt], acc2[0]);
          acc2[1] = MFMA16(h, w2f[1][kt], acc2[1]);
        }
        float part[2] = {0.f, 0.f};
        if (q < 2) {
#pragma unroll
          for (int r = 0; r < 4; ++r) {
            int j = q * 4 + r;
            bool m = (j < nvs) && (oiL[vslL[j]] != iv);
            if (m) {
              part[0] += lrelu(acc2[0][r] + b2v[0]);
              part[1] += lrelu(acc2[1][r] + b2v[1]);
            }
          }
        }
        part[0] += __shfl_xor(part[0], 16);
        part[1] += __shfl_xor(part[1], 16);
        if (q == 0) {
          featL[iv * 132 + (ng * 2 + 0) * 16 + n16] += part[0];
          featL[iv * 132 + (ng * 2 + 1) * 16 + n16] += part[1];
        }
      }
      __syncthreads();
    }
  }

  // ---------------- Phase E: infer_outfit + score ----------------
  if (tid < 128) {
    float sum = 0.0f;
    for (int u = 0; u < nvs; ++u) sum += featL[oiL[vslL[u]] * 132 + tid];
    float v = sum * o2sW[tid];
#pragma unroll
    for (int off = 1; off < 64; off <<= 1) v += __shfl_xor(v, off);
    if (lane == 0) redE[wid] = v;
  }
  __syncthreads();
  if (tid == 0) {
    float t = redE[0] + redE[1] + o2sb[0];
    out[o] = 1.0f / (1.0f + expf(-t));
  }

  // ---------------- Phase F: com_loss ----------------
  {
    const int n = tid >> 5, f = (tid >> 3) & 3, g = (tid >> 1) & 3, h = tid & 1;
    const float* pa = facL + n * 528 + f * 132 + h * 64;
    const float* pb = facL + n * 528 + g * 132 + h * 64;
    float dot = 0.0f;
    for (int i = 0; i < 16; ++i) {
      float4 a = *(const float4*)(pa + i * 4);
      float4 b = *(const float4*)(pb + i * 4);
      dot += a.x * b.x + a.y * b.y + a.z * b.z + a.w * b.w;
    }
    dot += __shfl_xor(dot, 1);  // combine k-halves
    float v = dot - ((f == g) ? 1.0f : 0.0f);
    float sq = (h == 0 && oiL[n] != -1) ? v * v : 0.0f;
#pragma unroll
    for (int off = 1; off < 64; off <<= 1) sq += __shfl_xor(sq, off);
    __syncthreads();  // ensure E's redE read done before overwrite
    if (lane == 0) redE[wid] = sq;
    __syncthreads();
    if (tid == 0) {
      float tot = 0.f;
#pragma unroll
      for (int w = 0; w < 8; ++w) tot += redE[w];
      atomicAdd(out + 2048, tot * (1.0f / 2048.0f));
    }
  }
}

extern "C" void kernel_launch(void* const* d_in, const int* in_sizes, int n_in,
                              void* d_out, int out_size, void* d_ws, size_t ws_size,
                              hipStream_t stream) {
  float* out = (float*)d_out;
  hipLaunchKernelGGL(zero_com, dim3(1), dim3(64), 0, stream, out);
  hipLaunchKernelGGL(mfgn_kernel, dim3(2048), dim3(512), 0, stream,
                     (const int*)d_in[0],
                     (const float*)d_in[1],
                     (const int*)d_in[2],
                     // d_in[3] items_factors unused (overwritten by creat_factors)
                     (const float*)d_in[4], (const float*)d_in[5],
                     (const float*)d_in[6], (const float*)d_in[7],
                     (const float*)d_in[8], (const float*)d_in[9],
                     (const float*)d_in[10], (const float*)d_in[11],
                     (const float*)d_in[12], (const float*)d_in[13],
                     (const float*)d_in[14], (const float*)d_in[15],
                     (const float*)d_in[16], (const float*)d_in[17],
                     (const float*)d_in[18], (const float*)d_in[19],
                     (const float*)d_in[20], (const float*)d_in[21],
                     out);
}

// Round 5
// 363.554 us; speedup vs baseline: 1.3990x; 1.3990x over previous
//
#include <hip/hip_runtime.h>
#include <hip/hip_bf16.h>
#include <math.h>

// MFGN forward, MI355X. One block (512 thr, 8 waves) per outfit.
// Each wave owns 16 output columns (wid*16..+15) in all MLP phases ->
// only 8 weight B-fragments per wave (32 VGPRs) -> no spill at
// __launch_bounds__(512,4) (R3 lesson: 32-col waves spilled 262MB scratch).
// L1 operand-swapped (A=W1^T, B=X^T) so hidden lands packable; L2 normal.

typedef __attribute__((ext_vector_type(8))) short short8;
typedef __attribute__((ext_vector_type(4))) float f32x4;

#define MFMA16(a, b, c) __builtin_amdgcn_mfma_f32_16x16x32_bf16(a, b, c, 0, 0, 0)

__device__ __forceinline__ float lrelu(float x) { return x > 0.0f ? x : 0.01f * x; }

__device__ __forceinline__ ushort f2bf(float f) {
  unsigned u = __builtin_bit_cast(unsigned, f);
  u += 0x7fffu + ((u >> 16) & 1u);  // RNE
  return (ushort)(u >> 16);
}

// packed f32x2 -> bf16x2 (v_cvt_pk_bf16_f32); low ushort = a
__device__ __forceinline__ unsigned pk2(float a, float b) {
  float2 t; t.x = a; t.y = b;
  __hip_bfloat162 h = __float22bfloat162_rn(t);
  unsigned u;
  __builtin_memcpy(&u, &h, 4);  // __hip_bfloat162 not trivially copyable
  return u;
}

// B-fragment gather from row-major fp32 W[k][ldn]: lane j -> W[kbase+j][col]
__device__ __forceinline__ short8 load_bfrag(const float* __restrict__ W, int ldn,
                                             int kbase, int col) {
  short8 r;
#pragma unroll
  for (int j = 0; j < 8; ++j) r[j] = (short)f2bf(W[(kbase + j) * ldn + col]);
  return r;
}

__global__ void zero_com(float* out) { if (threadIdx.x == 0) out[2048] = 0.0f; }

__global__ __launch_bounds__(512, 4) void mfgn_kernel(
    const int* __restrict__ outfit_items,
    const float* __restrict__ items_feature,
    const int* __restrict__ items_neighbor,
    const float* __restrict__ cfW1, const float* __restrict__ cfb1,
    const float* __restrict__ cfW2, const float* __restrict__ cfb2,
    const float* __restrict__ f2fW1, const float* __restrict__ f2fb1,
    const float* __restrict__ f2fW2, const float* __restrict__ f2fb2,
    const float* __restrict__ f2iW1, const float* __restrict__ f2ib1,
    const float* __restrict__ f2iW2, const float* __restrict__ f2ib2,
    const float* __restrict__ i2iW1, const float* __restrict__ i2ib1,
    const float* __restrict__ i2iW2, const float* __restrict__ i2ib2,
    const float* __restrict__ o2sW, const float* __restrict__ o2sb,
    float* __restrict__ out)
{
  __shared__ float facL[16 * 528];                               // fp32 [item][f][132]
  __shared__ float featL[16 * 132];                              // fp32 [item][132]
  __shared__ ushort Xa[64 * 136] __attribute__((aligned(16)));   // bf16 X rows (stride 272B)
  __shared__ ushort hidB[64 * 136] __attribute__((aligned(16))); // bf16 hidden rows
  __shared__ float redE[8];
  __shared__ int oiL[16];
  __shared__ int nbrL[128];
  __shared__ int clAll[16 * 16];
  __shared__ int ncAll[16];
  __shared__ int vslL[16];
  __shared__ int refcntL[16];
  __shared__ int nvsL;

  const int o = blockIdx.x;
  const int tid = (int)threadIdx.x;
  const int lane = tid & 63;
  const int wid = tid >> 6;       // 0..7 ; wave owns cols wid*16..+15
  const int n16 = lane & 15;
  const int q = lane >> 4;
  const int kb = q * 8;
  const int col = wid * 16 + n16; // this lane's output column (B-frag / epilogue)

  // ---------------- load inputs ----------------
  if (tid < 16) oiL[tid] = outfit_items[o * 16 + tid];
  if (tid < 128) nbrL[tid] = items_neighbor[o * 128 + tid];
  {
    const int n = tid >> 5, d0 = (tid & 31) * 4;
    float4 v = *(const float4*)(items_feature + o * 2048 + tid * 4);
    *(float4*)(featL + n * 132 + d0) = v;
    uint2 pk; pk.x = pk2(v.x, v.y); pk.y = pk2(v.z, v.w);
    *(uint2*)(Xa + n * 136 + d0) = pk;  // featB rows 0..15
  }
  if (tid == 0) {
    int cnt = 0;
    for (int s = 0; s < 16; ++s) refcntL[s] = 0;
    for (int s = 0; s < 16; ++s) {
      int v = oiL[s];
      if (v != -1) { vslL[cnt++] = s; refcntL[v]++; }
    }
    nvsL = cnt;
  }
  for (int s = wid; s < 16; s += 8) {
    const int iv = outfit_items[o * 16 + s];
    if (iv == -1) { if (lane == 0) ncAll[s] = 0; continue; }
    int cand = -1;
    if (lane < 24) cand = (lane < 16) ? outfit_items[o * 16 + lane]
                                      : items_neighbor[o * 128 + iv * 8 + (lane - 16)];
    bool ok = (lane < 24) && (cand != -1) && (cand != iv);
    unsigned long long bm = __ballot(ok);
    if (ok) clAll[s * 16 + __popcll(bm & ((1ull << lane) - 1ull))] = cand;
    if (lane == 0) ncAll[s] = (int)__popcll(bm);
  }
  __syncthreads();
  const int nvs = nvsL;

  // ---------------- Phase A: creat_factors ----------------
  {
    const int f = wid & 3, half = wid >> 2;
    // L1 swapped: H^T = W1^T * X^T ; wave covers 32 of 64 hidden cols
    short8 wA[2][4];
#pragma unroll
    for (int etl = 0; etl < 2; ++etl)
#pragma unroll
      for (int kt = 0; kt < 4; ++kt)
        wA[etl][kt] = load_bfrag(cfW1 + f * 8192, 64, kt * 32 + kb, (half * 2 + etl) * 16 + n16);
    f32x4 acc[2];
    acc[0] = (f32x4){0.f,0.f,0.f,0.f}; acc[1] = (f32x4){0.f,0.f,0.f,0.f};
    for (int kt = 0; kt < 4; ++kt) {
      short8 x = *(const short8*)(Xa + n16 * 136 + kt * 32 + kb);
      acc[0] = MFMA16(wA[0][kt], x, acc[0]);
      acc[1] = MFMA16(wA[1][kt], x, acc[1]);
    }
#pragma unroll
    for (int etl = 0; etl < 2; ++etl) {
      f32x4 b1q = *(const f32x4*)(cfb1 + f * 64 + (half * 2 + etl) * 16 + q * 4);
      float h0 = lrelu(acc[etl][0] + b1q[0]), h1 = lrelu(acc[etl][1] + b1q[1]);
      float h2 = lrelu(acc[etl][2] + b1q[2]), h3 = lrelu(acc[etl][3] + b1q[3]);
      uint2 pk; pk.x = pk2(h0, h1); pk.y = pk2(h2, h3);
      *(uint2*)(hidB + (f * 16 + n16) * 136 + (half * 2 + etl) * 16 + q * 4) = pk;
    }
    __syncthreads();
    // L2 normal: fac = H * W2[f], K=64 ; wave covers 64 of 128 cols
    short8 wB[4][2];
#pragma unroll
    for (int ctl = 0; ctl < 4; ++ctl)
#pragma unroll
      for (int kt = 0; kt < 2; ++kt)
        wB[ctl][kt] = load_bfrag(cfW2 + f * 8192, 128, kt * 32 + kb, half * 64 + ctl * 16 + n16);
    f32x4 acc2[4];
#pragma unroll
    for (int ctl = 0; ctl < 4; ++ctl) acc2[ctl] = (f32x4){0.f,0.f,0.f,0.f};
    for (int kt = 0; kt < 2; ++kt) {
      short8 h = *(const short8*)(hidB + (f * 16 + n16) * 136 + kt * 32 + kb);
#pragma unroll
      for (int ctl = 0; ctl < 4; ++ctl) acc2[ctl] = MFMA16(h, wB[ctl][kt], acc2[ctl]);
    }
#pragma unroll
    for (int ctl = 0; ctl < 4; ++ctl) {
      int c = half * 64 + ctl * 16 + n16;
      float b2 = cfb2[f * 128 + c];
#pragma unroll
      for (int r = 0; r < 4; ++r)
        facL[(q * 4 + r) * 528 + f * 132 + c] = lrelu(acc2[ctl][r] + b2);
    }
    __syncthreads();
  }

  // ---------------- Phase B: inter_factors ----------------
  {
    short8 w1f[4], w2f[4];
#pragma unroll
    for (int kt = 0; kt < 4; ++kt) {
      w1f[kt] = load_bfrag(f2fW1, 128, kt * 32 + kb, col);
      w2f[kt] = load_bfrag(f2fW2, 128, kt * 32 + kb, col);
    }
    const f32x4 b1q = *(const f32x4*)(f2fb1 + wid * 16 + q * 4);
    const float b2v = f2fb2[col];
    const int rS = tid >> 3, kcS = tid & 7;      // staging: row, 16-k chunk
    const int fS = rS & 3, ciS = rS >> 2;
    const int k0 = kcS * 16;

    for (int s = 0; s < 16; ++s) {
      const int iv = oiL[s];
      if (iv == -1) continue;
      const int nc = ncAll[s];
      // stage Xa[r=ci*4+f][k] = bf16(fac[iv][f][k] * fac[cand][f][k])
      if (ciS < nc) {
        const int cit = clAll[s * 16 + ciS];
        const float* tp = facL + iv * 528 + fS * 132;
        const float* cp = facL + cit * 528 + fS * 132;
#pragma unroll
        for (int i2 = 0; i2 < 2; ++i2) {
          const int k = k0 + i2 * 8;
          float4 a0 = *(const float4*)(tp + k), a1 = *(const float4*)(tp + k + 4);
          float4 c0 = *(const float4*)(cp + k), c1 = *(const float4*)(cp + k + 4);
          uint4 u;
          u.x = pk2(a0.x * c0.x, a0.y * c0.y); u.y = pk2(a0.z * c0.z, a0.w * c0.w);
          u.z = pk2(a1.x * c1.x, a1.y * c1.y); u.w = pk2(a1.z * c1.z, a1.w * c1.w);
          *(uint4*)(Xa + rS * 136 + k) = u;
        }
      } else {
        uint4 z; z.x = z.y = z.z = z.w = 0;
        *(uint4*)(Xa + rS * 136 + k0) = z;
        *(uint4*)(Xa + rS * 136 + k0 + 8) = z;
      }
      __syncthreads();
      // L1 swapped: lane -> H[row=mt*16+n16][e=wid*16+q*4+reg]
      f32x4 acc[4];
#pragma unroll
      for (int mt = 0; mt < 4; ++mt) acc[mt] = (f32x4){0.f,0.f,0.f,0.f};
      for (int kt = 0; kt < 4; ++kt)
#pragma unroll
        for (int mt = 0; mt < 4; ++mt) {
          short8 x = *(const short8*)(Xa + (mt * 16 + n16) * 136 + kt * 32 + kb);
          acc[mt] = MFMA16(w1f[kt], x, acc[mt]);
        }
      __syncthreads();  // all waves done reading Xa
#pragma unroll
      for (int mt = 0; mt < 4; ++mt) {
        float h0 = lrelu(acc[mt][0] + b1q[0]), h1 = lrelu(acc[mt][1] + b1q[1]);
        float h2 = lrelu(acc[mt][2] + b1q[2]), h3 = lrelu(acc[mt][3] + b1q[3]);
        uint2 pk; pk.x = pk2(h0, h1); pk.y = pk2(h2, h3);
        *(uint2*)(hidB + (mt * 16 + n16) * 136 + wid * 16 + q * 4) = pk;
      }
      __syncthreads();
      // L2 normal: lane -> Y[r=mt*16+q*4+reg][c=col]
      f32x4 acc2[4];
#pragma unroll
      for (int mt = 0; mt < 4; ++mt) acc2[mt] = (f32x4){0.f,0.f,0.f,0.f};
      for (int kt = 0; kt < 4; ++kt)
#pragma unroll
        for (int mt = 0; mt < 4; ++mt) {
          short8 h = *(const short8*)(hidB + (mt * 16 + n16) * 136 + kt * 32 + kb);
          acc2[mt] = MFMA16(h, w2f[kt], acc2[mt]);
        }
      // epilogue: rows are ci*4+f (f=reg r); mask ci=mt*4+q<nc; sum over ci
      float part[4] = {0.f, 0.f, 0.f, 0.f};
#pragma unroll
      for (int mt = 0; mt < 4; ++mt) {
        bool act = (mt * 4 + q) < nc;
        if (act)
#pragma unroll
          for (int r = 0; r < 4; ++r) part[r] += lrelu(acc2[mt][r] + b2v);
      }
#pragma unroll
      for (int r = 0; r < 4; ++r) {
        float v = part[r];
        v += __shfl_xor(v, 16);
        v += __shfl_xor(v, 32);
        part[r] = v;
      }
      if (q == 0) {  // wave owns cols exclusively -> plain +=
#pragma unroll
        for (int r = 0; r < 4; ++r)
          facL[iv * 528 + r * 132 + col] += part[r];
      }
      __syncthreads();
    }
  }

  // ---------------- Phase C: infer_items ----------------
  {
    short8 w1f[4], w2f[4];
#pragma unroll
    for (int kt = 0; kt < 4; ++kt) {
      w1f[kt] = load_bfrag(f2iW1, 128, kt * 32 + kb, col);
      w2f[kt] = load_bfrag(f2iW2, 128, kt * 32 + kb, col);
    }
    const f32x4 b1q = *(const f32x4*)(f2ib1 + wid * 16 + q * 4);
    const float b2v = f2ib2[col];
    // stage Xa[r=item*4+f][k] = bf16(fac[item][f][k])
    {
      const int r = tid >> 3, kc = tid & 7, k0 = kc * 16;
      const int f = r & 3, item = r >> 2;
      const float* sp = facL + item * 528 + f * 132;
#pragma unroll
      for (int i2 = 0; i2 < 2; ++i2) {
        const int k = k0 + i2 * 8;
        float4 a0 = *(const float4*)(sp + k), a1 = *(const float4*)(sp + k + 4);
        uint4 u;
        u.x = pk2(a0.x, a0.y); u.y = pk2(a0.z, a0.w);
        u.z = pk2(a1.x, a1.y); u.w = pk2(a1.z, a1.w);
        *(uint4*)(Xa + r * 136 + k) = u;
      }
    }
    __syncthreads();
    f32x4 acc[4];
#pragma unroll
    for (int mt = 0; mt < 4; ++mt) acc[mt] = (f32x4){0.f,0.f,0.f,0.f};
    for (int kt = 0; kt < 4; ++kt)
#pragma unroll
      for (int mt = 0; mt < 4; ++mt) {
        short8 x = *(const short8*)(Xa + (mt * 16 + n16) * 136 + kt * 32 + kb);
        acc[mt] = MFMA16(w1f[kt], x, acc[mt]);
      }
    __syncthreads();
#pragma unroll
    for (int mt = 0; mt < 4; ++mt) {
      float h0 = lrelu(acc[mt][0] + b1q[0]), h1 = lrelu(acc[mt][1] + b1q[1]);
      float h2 = lrelu(acc[mt][2] + b1q[2]), h3 = lrelu(acc[mt][3] + b1q[3]);
      uint2 pk; pk.x = pk2(h0, h1); pk.y = pk2(h2, h3);
      *(uint2*)(hidB + (mt * 16 + n16) * 136 + wid * 16 + q * 4) = pk;
    }
    __syncthreads();
    f32x4 acc2[4];
#pragma unroll
    for (int mt = 0; mt < 4; ++mt) acc2[mt] = (f32x4){0.f,0.f,0.f,0.f};
    for (int kt = 0; kt < 4; ++kt)
#pragma unroll
      for (int mt = 0; mt < 4; ++mt) {
        short8 h = *(const short8*)(hidB + (mt * 16 + n16) * 136 + kt * 32 + kb);
        acc2[mt] = MFMA16(h, w2f[kt], acc2[mt]);
      }
#pragma unroll
    for (int mt = 0; mt < 4; ++mt) {
      int item = mt * 4 + q;  // rows = item*4+f, f=reg
      float g = 0.f;
#pragma unroll
      for (int r = 0; r < 4; ++r) g += lrelu(acc2[mt][r] + b2v);
      featL[item * 132 + col] += (float)refcntL[item] * g;  // exclusive col
    }
    __syncthreads();
  }

  // ---------------- Phase D: inter_items ----------------
  {
    short8 w1f[4], w2f[4];
#pragma unroll
    for (int kt = 0; kt < 4; ++kt) {
      w1f[kt] = load_bfrag(i2iW1, 128, kt * 32 + kb, col);
      w2f[kt] = load_bfrag(i2iW2, 128, kt * 32 + kb, col);
    }
    const f32x4 b1q = *(const f32x4*)(i2ib1 + wid * 16 + q * 4);
    const float b2v = i2ib2[col];
    const int rS = tid >> 3, kcS = tid & 7, k0 = kcS * 16;

    for (int u = 0; u < nvs; ++u) {
      const int iv = oiL[vslL[u]];
      // stage Xa rows j<nvs from current feat
      if (rS < nvs) {
        const int it = oiL[vslL[rS]];
        const float* sp = featL + it * 132;
#pragma unroll
        for (int i2 = 0; i2 < 2; ++i2) {
          const int k = k0 + i2 * 8;
          float4 a0 = *(const float4*)(sp + k), a1 = *(const float4*)(sp + k + 4);
          uint4 uu;
          uu.x = pk2(a0.x, a0.y); uu.y = pk2(a0.z, a0.w);
          uu.z = pk2(a1.x, a1.y); uu.w = pk2(a1.z, a1.w);
          *(uint4*)(Xa + rS * 136 + k) = uu;
        }
      }
      __syncthreads();
      // L1 swapped on 16 rows (rows >= nvs garbage, masked later)
      f32x4 acc;
      acc = (f32x4){0.f,0.f,0.f,0.f};
      for (int kt = 0; kt < 4; ++kt) {
        short8 x = *(const short8*)(Xa + n16 * 136 + kt * 32 + kb);
        acc = MFMA16(w1f[kt], x, acc);
      }
      __syncthreads();
      {
        float h0 = lrelu(acc[0] + b1q[0]), h1 = lrelu(acc[1] + b1q[1]);
        float h2 = lrelu(acc[2] + b1q[2]), h3 = lrelu(acc[3] + b1q[3]);
        uint2 pk; pk.x = pk2(h0, h1); pk.y = pk2(h2, h3);
        *(uint2*)(hidB + n16 * 136 + wid * 16 + q * 4) = pk;
      }
      __syncthreads();
      f32x4 acc2;
      acc2 = (f32x4){0.f,0.f,0.f,0.f};
      for (int kt = 0; kt < 4; ++kt) {
        short8 h = *(const short8*)(hidB + n16 * 136 + kt * 32 + kb);
        acc2 = MFMA16(h, w2f[kt], acc2);
      }
      float part = 0.f;
      if (q < 2) {
#pragma unroll
        for (int r = 0; r < 4; ++r) {
          int j = q * 4 + r;
          bool m = (j < nvs) && (oiL[vslL[j]] != iv);
          if (m) part += lrelu(acc2[r] + b2v);
        }
      }
      part += __shfl_xor(part, 16);
      if (q == 0) featL[iv * 132 + col] += part;  // exclusive col
      __syncthreads();
    }
  }

  // ---------------- Phase E: infer_outfit + score ----------------
  if (tid < 128) {
    float sum = 0.0f;
    for (int u = 0; u < nvs; ++u) sum += featL[oiL[vslL[u]] * 132 + tid];
    float v = sum * o2sW[tid];
#pragma unroll
    for (int off = 1; off < 64; off <<= 1) v += __shfl_xor(v, off);
    if (lane == 0) redE[wid] = v;
  }
  __syncthreads();
  if (tid == 0) {
    float t = redE[0] + redE[1] + o2sb[0];
    out[o] = 1.0f / (1.0f + expf(-t));
  }

  // ---------------- Phase F: com_loss ----------------
  {
    const int n = tid >> 5, f = (tid >> 3) & 3, g = (tid >> 1) & 3, h = tid & 1;
    const float* pa = facL + n * 528 + f * 132 + h * 64;
    const float* pb = facL + n * 528 + g * 132 + h * 64;
    float dot = 0.0f;
    for (int i = 0; i < 16; ++i) {
      float4 a = *(const float4*)(pa + i * 4);
      float4 b = *(const float4*)(pb + i * 4);
      dot += a.x * b.x + a.y * b.y + a.z * b.z + a.w * b.w;
    }
    dot += __shfl_xor(dot, 1);  // combine k-halves
    float v = dot - ((f == g) ? 1.0f : 0.0f);
    float sq = (h == 0 && oiL[n] != -1) ? v * v : 0.0f;
#pragma unroll
    for (int off = 1; off < 64; off <<= 1) sq += __shfl_xor(sq, off);
    __syncthreads();  // ensure E's redE read done before overwrite
    if (lane == 0) redE[wid] = sq;
    __syncthreads();
    if (tid == 0) {
      float tot = 0.f;
#pragma unroll
      for (int w = 0; w < 8; ++w) tot += redE[w];
      atomicAdd(out + 2048, tot * (1.0f / 2048.0f));
    }
  }
}

extern "C" void kernel_launch(void* const* d_in, const int* in_sizes, int n_in,
                              void* d_out, int out_size, void* d_ws, size_t ws_size,
                              hipStream_t stream) {
  float* out = (float*)d_out;
  hipLaunchKernelGGL(zero_com, dim3(1), dim3(64), 0, stream, out);
  hipLaunchKernelGGL(mfgn_kernel, dim3(2048), dim3(512), 0, stream,
                     (const int*)d_in[0],
                     (const float*)d_in[1],
                     (const int*)d_in[2],
                     // d_in[3] items_factors unused (overwritten by creat_factors)
                     (const float*)d_in[4], (const float*)d_in[5],
                     (const float*)d_in[6], (const float*)d_in[7],
                     (const float*)d_in[8], (const float*)d_in[9],
                     (const float*)d_in[10], (const float*)d_in[11],
                     (const float*)d_in[12], (const float*)d_in[13],
                     (const float*)d_in[14], (const float*)d_in[15],
                     (const float*)d_in[16], (const float*)d_in[17],
                     (const float*)d_in[18], (const float*)d_in[19],
                     (const float*)d_in[20], (const float*)d_in[21],
                     out);
}